// Round 8
// baseline (377.285 us; speedup 1.0000x reference)
//
#include <hip/hip_runtime.h>
#include <cfloat>

#define GT 16
#define NCLS 81
#define TPB 256
#define BPT 1024
#define MAXP 8732
#define TROWS 64

__device__ __forceinline__ float smoothl1(float d){
  float a = fabsf(d);
  return a < 1.0f ? 0.5f*a*a : a - 0.5f;
}

// unaligned float4 load (global multi-dword needs only 4B alignment on gfx9+;
// emits global_load_dwordx4 align 4)
__device__ __forceinline__ float4 ld4u(const float* p){
  float4 v;
  __builtin_memcpy(&v, p, sizeof(float4));
  return v;
}

// Kernel 1: per-(batch,gt) best prior via block-local reduction.
__global__ __launch_bounds__(BPT) void bestprior(
    const float* __restrict__ priors,     // (P,4) xywh
    const float* __restrict__ gt_boxes,   // (B,GT,4) xyxy
    int*   __restrict__ best,             // (B,GT) prior index
    float* __restrict__ ce_pos, float* __restrict__ sl1_sum,
    int* __restrict__ num_pos, float* __restrict__ out, int P)
{
  const int b = blockIdx.x;
  const int tid = threadIdx.x, wave = tid >> 6, lane = tid & 63;
  __shared__ float gx0[GT], gy0[GT], gx1[GT], gy1[GT], ga[GT];
  __shared__ float redv[16*GT]; __shared__ int redi[16*GT];
  if (tid == 0){ ce_pos[b] = 0.0f; sl1_sum[b] = 0.0f; num_pos[b] = 0; }
  if (b == 0 && tid < 2) out[tid] = 0.0f;
  if (tid < GT){
    const float4 gb = ((const float4*)gt_boxes)[b*GT + tid];
    gx0[tid]=gb.x; gy0[tid]=gb.y; gx1[tid]=gb.z; gy1[tid]=gb.w;
    ga[tid] = (gb.z-gb.x)*(gb.w-gb.y);
  }
  __syncthreads();
  float bv[GT]; int bi[GT];
  #pragma unroll
  for (int g=0; g<GT; ++g){ bv[g] = -1.0f; bi[g] = 0x7fffffff; }
  for (int p = tid; p < P; p += BPT){          // ascending p per thread
    const float4 pr = ((const float4*)priors)[p];
    const float px0 = pr.x - pr.z*0.5f, py0 = pr.y - pr.w*0.5f;
    const float px1 = pr.x + pr.z*0.5f, py1 = pr.y + pr.w*0.5f;
    const float pa = (px1-px0)*(py1-py0);
    #pragma unroll
    for (int g=0; g<GT; ++g){
      const float w = fmaxf(fminf(gx1[g],px1) - fmaxf(gx0[g],px0), 0.0f);
      const float h = fmaxf(fminf(gy1[g],py1) - fmaxf(gy0[g],py0), 0.0f);
      const float inter = w*h;
      const float iou = inter / (ga[g] + pa - inter);
      if (iou > bv[g]){ bv[g] = iou; bi[g] = p; }   // first-max over p
    }
  }
  #pragma unroll
  for (int g=0; g<GT; ++g){
    float v = bv[g]; int i = bi[g];
    for (int off=32; off>0; off>>=1){
      const float ov = __shfl_down(v, off);
      const int   oi = __shfl_down(i, off);
      if (ov > v || (ov == v && oi < i)){ v = ov; i = oi; } // smaller p on tie
    }
    if (lane == 0){ redv[wave*GT+g] = v; redi[wave*GT+g] = i; }
  }
  __syncthreads();
  if (tid < GT){
    float v = redv[tid]; int i = redi[tid];
    for (int w=1; w<16; ++w){
      const float ov = redv[w*GT+tid]; const int oi = redi[w*GT+tid];
      if (ov > v || (ov == v && oi < i)){ v = ov; i = oi; }
    }
    best[b*GT + tid] = i;
  }
}

// Kernel 2: fused assign + LSE, ROW-PER-LANE direct-global.
// R6's quad-span layout scattered each dword load's 64 lanes over only 16
// rows -> ~64 distinct 64B lines per VMEM instruction x 21 instructions
// per 16 rows = ~84 line-requests/row. At ~1 line/cycle in the CU's TCP
// that's ~77 us of pure address processing -- the ~110 us invariant
// (R0-R5 paid the same wall via the LDS serial structure instead). Now
// each LANE owns one full row, loaded as 20 UNALIGNED dwordx4 + 1 dword:
// one wave-iteration covers 64 rows -> ~21 line-requests/row, 4x less TA.
// LSE is fully lane-local (no shfl/LDS); bg[] store is wave-coalesced.
// All FP sequences are BIT-IDENTICAL to R6: span sums s0..s3 ascending,
// combined (s0+s1)+(s2+s3); serial first-max assign == quad-reduce;
// x[lab] re-read from global.
// NOTE: __launch_bounds__(TPB) ONLY -- a min-waves/EU clause (R2) spills.
__global__ __launch_bounds__(TPB) void fused_lse(
    const float* __restrict__ priors,     // (P,4) xywh
    const float* __restrict__ gt_boxes,   // (B,GT,4) xyxy
    const int*   __restrict__ gt_labels,  // (B,GT)
    const float* __restrict__ box_reg,    // (B,P,4)
    const int*   __restrict__ best,       // (B,GT)
    const float* __restrict__ logits,     // (B*P, 81)
    float* __restrict__ bg,               // (B*P)
    float* __restrict__ ce_pos,           // (B)
    float* __restrict__ sl1_sum,          // (B)
    int*   __restrict__ num_pos,          // (B)
    int P, int NT)                        // NT = B*P/TROWS = 8732 exact
{
  __shared__ float sgx0[2][GT], sgy0[2][GT], sgx1[2][GT], sgy1[2][GT], sga[2][GT];
  __shared__ int   slab[2][GT], sbp[2][GT];
  const int tid = threadIdx.x;
  const int wave = tid >> 6, lane = tid & 63;
  const int G = gridDim.x;

  // contiguous tile range for this block (span <= ~8 tiles -> <= 2 batches)
  const int qn = NT / G, rn = NT % G;
  const int k = blockIdx.x;
  const int t0  = k < rn ? k*(qn+1) : rn*(qn+1) + (k-rn)*qn;
  const int cnt = k < rn ? qn+1 : qn;
  if (cnt <= 0) return;
  const int tend = t0 + cnt;
  const int b0 = (t0*TROWS)/P;
  const int b1 = (tend*TROWS - 1)/P;      // <= b0+1
  const int boundary = b1*P;              // row >= boundary -> slot 1

  if (tid < 2*GT){                        // stage gt data for both batches
    const int slot = tid >> 4, g = tid & 15;
    const int bb = slot ? b1 : b0;
    const float4 gb = ((const float4*)gt_boxes)[bb*GT + g];
    sgx0[slot][g]=gb.x; sgy0[slot][g]=gb.y; sgx1[slot][g]=gb.z; sgy1[slot][g]=gb.w;
    sga[slot][g] = (gb.z-gb.x)*(gb.w-gb.y);
    slab[slot][g] = gt_labels[bb*GT + g];
    sbp[slot][g]  = best[bb*GT + g];
  }
  __syncthreads();                        // one-time; loop is barrier-free

  for (int t = t0 + wave; t < tend; t += 4){   // one 64-row tile per wave
    const int row = t*TROWS + lane;
    const int slot = (row >= boundary);
    const int b = slot ? b1 : b0;
    const int p = row - b*P;
    const float* xr = logits + (long long)row*NCLS;

    const float4 pr = ((const float4*)priors)[p];
    const float4 br = ((const float4*)box_reg)[row];

    // ---- per-lane assignment over 16 GT (== R4-R6 semantics exactly) ----
    const float px0 = pr.x - pr.z*0.5f, py0 = pr.y - pr.w*0.5f;
    const float px1 = pr.x + pr.z*0.5f, py1 = pr.y + pr.w*0.5f;
    const float pa  = (px1-px0)*(py1-py0);
    float mv = -1.0f; int mi = 0;
    #pragma unroll
    for (int g=0; g<GT; ++g){             // ascending: first-max over g
      const float w = fmaxf(fminf(sgx1[slot][g],px1) - fmaxf(sgx0[slot][g],px0), 0.0f);
      const float h = fmaxf(fminf(sgy1[slot][g],py1) - fmaxf(sgy0[slot][g],py0), 0.0f);
      const float inter = w*h;
      const float iou = inter / (sga[slot][g] + pa - inter);
      if (iou > mv){ mv = iou; mi = g; }
    }
    #pragma unroll
    for (int g2=0; g2<GT; ++g2)
      if (sbp[slot][g2] == p){ mv = 2.0f; mi = g2; }   // last g wins

    int lab = 0; float sl1v = 0.0f;
    if (mv >= 0.5f){
      lab = slab[slot][mi];
      const float gbx0 = sgx0[slot][mi], gby0 = sgy0[slot][mi];
      const float gbx1 = sgx1[slot][mi], gby1 = sgy1[slot][mi];
      const float ctrx = (gbx0+gbx1)*0.5f, ctry = (gby0+gby1)*0.5f;
      const float wx = gbx1-gbx0, wy = gby1-gby0;
      const float tx = (ctrx - pr.x) / (0.1f*pr.z);
      const float ty = (ctry - pr.y) / (0.1f*pr.w);
      const float tw = __logf(wx/pr.z) / 0.2f;
      const float th = __logf(wy/pr.w) / 0.2f;
      sl1v = smoothl1(br.x - tx) + smoothl1(br.y - ty)
           + smoothl1(br.z - tw) + smoothl1(br.w - th);
    }

    // ---- LSE: 4 spans, ascending adds, combine (s0+s1)+(s2+s3) ----
    // Identical FP sequence to R6's quad version.
    float4 a0 = ld4u(xr+ 0), a1 = ld4u(xr+ 4), a2 = ld4u(xr+ 8),
           a3 = ld4u(xr+12), a4 = ld4u(xr+16);
    const float x20 = xr[20];
    const float x0v = a0.x;
    float s0 = __expf(a0.x);
    s0 += __expf(a0.y); s0 += __expf(a0.z); s0 += __expf(a0.w);
    s0 += __expf(a1.x); s0 += __expf(a1.y); s0 += __expf(a1.z); s0 += __expf(a1.w);
    s0 += __expf(a2.x); s0 += __expf(a2.y); s0 += __expf(a2.z); s0 += __expf(a2.w);
    s0 += __expf(a3.x); s0 += __expf(a3.y); s0 += __expf(a3.z); s0 += __expf(a3.w);
    s0 += __expf(a4.x); s0 += __expf(a4.y); s0 += __expf(a4.z); s0 += __expf(a4.w);
    s0 += __expf(x20);

    float4 c0 = ld4u(xr+21), c1 = ld4u(xr+25), c2 = ld4u(xr+29),
           c3 = ld4u(xr+33), c4 = ld4u(xr+37);
    float s1 = __expf(c0.x);
    s1 += __expf(c0.y); s1 += __expf(c0.z); s1 += __expf(c0.w);
    s1 += __expf(c1.x); s1 += __expf(c1.y); s1 += __expf(c1.z); s1 += __expf(c1.w);
    s1 += __expf(c2.x); s1 += __expf(c2.y); s1 += __expf(c2.z); s1 += __expf(c2.w);
    s1 += __expf(c3.x); s1 += __expf(c3.y); s1 += __expf(c3.z); s1 += __expf(c3.w);
    s1 += __expf(c4.x); s1 += __expf(c4.y); s1 += __expf(c4.z); s1 += __expf(c4.w);

    float4 d0 = ld4u(xr+41), d1 = ld4u(xr+45), d2 = ld4u(xr+49),
           d3 = ld4u(xr+53), d4 = ld4u(xr+57);
    float s2 = __expf(d0.x);
    s2 += __expf(d0.y); s2 += __expf(d0.z); s2 += __expf(d0.w);
    s2 += __expf(d1.x); s2 += __expf(d1.y); s2 += __expf(d1.z); s2 += __expf(d1.w);
    s2 += __expf(d2.x); s2 += __expf(d2.y); s2 += __expf(d2.z); s2 += __expf(d2.w);
    s2 += __expf(d3.x); s2 += __expf(d3.y); s2 += __expf(d3.z); s2 += __expf(d3.w);
    s2 += __expf(d4.x); s2 += __expf(d4.y); s2 += __expf(d4.z); s2 += __expf(d4.w);

    float4 e0 = ld4u(xr+61), e1 = ld4u(xr+65), e2 = ld4u(xr+69),
           e3 = ld4u(xr+73), e4 = ld4u(xr+77);
    float s3 = __expf(e0.x);
    s3 += __expf(e0.y); s3 += __expf(e0.z); s3 += __expf(e0.w);
    s3 += __expf(e1.x); s3 += __expf(e1.y); s3 += __expf(e1.z); s3 += __expf(e1.w);
    s3 += __expf(e2.x); s3 += __expf(e2.y); s3 += __expf(e2.z); s3 += __expf(e2.w);
    s3 += __expf(e3.x); s3 += __expf(e3.y); s3 += __expf(e3.z); s3 += __expf(e3.w);
    s3 += __expf(e4.x); s3 += __expf(e4.y); s3 += __expf(e4.z); s3 += __expf(e4.w);

    const float sum = (s0 + s1) + (s2 + s3);
    const float lse = __logf(sum);
    float bgv;
    if (lab > 0){
      atomicAdd(&ce_pos[b], lse - xr[lab]);   // rare; L1-hot line
      atomicAdd(&sl1_sum[b], sl1v);
      atomicAdd(&num_pos[b], 1);
      bgv = 0.0f;
    } else {
      bgv = fmaxf(lse - x0v, 0.0f);           // clamp: radix needs >=0
    }
    bg[row] = bgv;                            // coalesced 64-dword store
  }
}

// Kernel 3: per-batch top-(3*num_pos) sum. Count-only 8-bit radix select
// (16 replicated histograms, stride 257), final pass sums values strictly
// above threshold; ties contribute krem * threshold. Fused final /N reduce.
__global__ __launch_bounds__(TPB) void topk_kernel(
    const float* __restrict__ bg,
    const int*   __restrict__ num_pos,
    const float* __restrict__ sl1_sum,
    const float* __restrict__ ce_pos,
    float* __restrict__ out,
    int P, int B)
{
  const int b = blockIdx.x;
  const int tid = threadIdx.x;
  const int wave = tid >> 6, lane = tid & 63;
  const int rep = tid & 15;
  __shared__ float sv[MAXP];
  __shared__ unsigned cntR[16][257];    // padded: bank = (rep*257+bin)%32
  __shared__ unsigned s_wc[4];
  __shared__ float    s_wf[4];
  __shared__ unsigned s_prefix;
  __shared__ int s_krem, s_chosen, s_newk;

  {
    const float4* srcp = (const float4*)(bg + (long long)b * P);
    float4* dst = (float4*)sv;
    for (int j = tid; j < P/4; j += TPB) dst[j] = srcp[j];
  }
  if (tid == 0){
    const int k = 3*num_pos[b];
    s_krem = k < P ? k : P-1;
    s_prefix = 0u;
  }
  __syncthreads();

  for (int level=0; level<4; ++level){
    const int shift = 24 - 8*level;
    for (int i = tid; i < 16*257; i += TPB) ((unsigned*)cntR)[i] = 0u;
    __syncthreads();
    const unsigned pref = s_prefix;
    const int k = s_krem;
    for (int j = tid; j < P/4; j += TPB){
      const float4 f4 = ((const float4*)sv)[j];
      #pragma unroll
      for (int e=0; e<4; ++e){
        const unsigned key = __float_as_uint((&f4.x)[e]);
        const bool ok = (level == 0) || ((key >> (shift+8)) == pref);
        if (ok) atomicAdd(&cntR[rep][(key >> shift) & 255u], 1u);
      }
    }
    __syncthreads();
    const int rb = 255 - tid;
    unsigned c = 0;
    #pragma unroll
    for (int r=0; r<16; ++r) c += cntR[r][rb];
    unsigned cv = c;
    #pragma unroll
    for (int off=1; off<64; off<<=1){
      const unsigned oc = __shfl_up(cv, off);
      if (lane >= off) cv += oc;
    }
    if (lane == 63) s_wc[wave] = cv;
    __syncthreads();
    unsigned addc = 0;
    for (int w=0; w<4; ++w) if (w < wave) addc += s_wc[w];
    const unsigned S = cv - c + addc;   // count in bins > rb (matching prefix)
    if ((int)S <= k && k < (int)(S + c)){
      s_chosen = rb; s_newk = k - (int)S;      // exactly one thread
    }
    __syncthreads();
    if (tid == 0){
      s_krem = s_newk;
      s_prefix = (pref << 8) | (unsigned)s_chosen;
    }
    __syncthreads();
  }
  // final pass: sum of values strictly above threshold
  const unsigned T = s_prefix;
  float acc = 0.0f;
  for (int j = tid; j < P/4; j += TPB){
    const float4 f4 = ((const float4*)sv)[j];
    #pragma unroll
    for (int e=0; e<4; ++e){
      const float f = (&f4.x)[e];
      if (__float_as_uint(f) > T) acc += f;
    }
  }
  for (int off=32; off>0; off>>=1) acc += __shfl_down(acc, off);
  if (lane == 0) s_wf[wave] = acc;
  __syncthreads();
  if (tid < 64){                        // wave 0: N = sum(num_pos), /N shares
    float n = 0.0f;
    for (int i = tid; i < B; i += 64) n += (float)num_pos[i];
    for (int off=32; off>0; off>>=1) n += __shfl_down(n, off);
    if (tid == 0){
      const float N = n;
      const float cls = s_wf[0]+s_wf[1]+s_wf[2]+s_wf[3]
                      + (float)s_krem * __uint_as_float(T);
      atomicAdd(&out[0], sl1_sum[b] / N);
      atomicAdd(&out[1], (ce_pos[b] + cls) / N);
    }
  }
}

extern "C" void kernel_launch(void* const* d_in, const int* in_sizes, int n_in,
                              void* d_out, int out_size, void* d_ws, size_t ws_size,
                              hipStream_t stream) {
  const float* priors = (const float*)d_in[0];
  const float* logits = (const float*)d_in[1];
  const float* boxreg = (const float*)d_in[2];
  const float* gtb    = (const float*)d_in[3];
  const int*   gtl    = (const int*)d_in[4];
  const int P = in_sizes[0] / 4;          // 8732
  const int B = in_sizes[4] / GT;         // 64
  const long long BP = (long long)B * P;

  char* ws = (char*)d_ws;
  float* bgv  = (float*)ws;                             // BP float
  int*   best = (int*)(ws + BP*4);                      // B*GT int
  float* sl1_s= (float*)(ws + BP*4 + 4096);
  int*   npos = (int*)  (ws + BP*4 + 4352);
  float* cep  = (float*)(ws + BP*4 + 4608);

  bestprior<<<B, BPT, 0, stream>>>(priors, gtb, best, cep, sl1_s, npos,
                                   (float*)d_out, P);
  const int NT = (int)(BP / TROWS);       // 8732 exact
  const int G = 2048;                     // 8192 waves, ~1.07 tiles/wave
  fused_lse<<<G, TPB, 0, stream>>>(priors, gtb, gtl, boxreg, best, logits,
                                   bgv, cep, sl1_s, npos, P, NT);
  topk_kernel<<<B, TPB, 0, stream>>>(bgv, npos, sl1_s, cep, (float*)d_out, P, B);
}

// Round 9
// 364.579 us; speedup vs baseline: 1.0349x; 1.0349x over previous
//
#include <hip/hip_runtime.h>
#include <cfloat>

#define GT 16
#define NCLS 81
#define TPB 256
#define BPT 1024
#define MAXP 8732

__device__ __forceinline__ float smoothl1(float d){
  float a = fabsf(d);
  return a < 1.0f ? 0.5f*a*a : a - 0.5f;
}

// Kernel 1: per-(batch,gt) best prior via block-local reduction.
__global__ __launch_bounds__(BPT) void bestprior(
    const float* __restrict__ priors,     // (P,4) xywh
    const float* __restrict__ gt_boxes,   // (B,GT,4) xyxy
    int*   __restrict__ best,             // (B,GT) prior index
    float* __restrict__ ce_pos, float* __restrict__ sl1_sum,
    int* __restrict__ num_pos, float* __restrict__ out, int P)
{
  const int b = blockIdx.x;
  const int tid = threadIdx.x, wave = tid >> 6, lane = tid & 63;
  __shared__ float gx0[GT], gy0[GT], gx1[GT], gy1[GT], ga[GT];
  __shared__ float redv[16*GT]; __shared__ int redi[16*GT];
  if (tid == 0){ ce_pos[b] = 0.0f; sl1_sum[b] = 0.0f; num_pos[b] = 0; }
  if (b == 0 && tid < 2) out[tid] = 0.0f;
  if (tid < GT){
    const float4 gb = ((const float4*)gt_boxes)[b*GT + tid];
    gx0[tid]=gb.x; gy0[tid]=gb.y; gx1[tid]=gb.z; gy1[tid]=gb.w;
    ga[tid] = (gb.z-gb.x)*(gb.w-gb.y);
  }
  __syncthreads();
  float bv[GT]; int bi[GT];
  #pragma unroll
  for (int g=0; g<GT; ++g){ bv[g] = -1.0f; bi[g] = 0x7fffffff; }
  for (int p = tid; p < P; p += BPT){          // ascending p per thread
    const float4 pr = ((const float4*)priors)[p];
    const float px0 = pr.x - pr.z*0.5f, py0 = pr.y - pr.w*0.5f;
    const float px1 = pr.x + pr.z*0.5f, py1 = pr.y + pr.w*0.5f;
    const float pa = (px1-px0)*(py1-py0);
    #pragma unroll
    for (int g=0; g<GT; ++g){
      const float w = fmaxf(fminf(gx1[g],px1) - fmaxf(gx0[g],px0), 0.0f);
      const float h = fmaxf(fminf(gy1[g],py1) - fmaxf(gy0[g],py0), 0.0f);
      const float inter = w*h;
      const float iou = inter / (ga[g] + pa - inter);
      if (iou > bv[g]){ bv[g] = iou; bi[g] = p; }   // first-max over p
    }
  }
  #pragma unroll
  for (int g=0; g<GT; ++g){
    float v = bv[g]; int i = bi[g];
    for (int off=32; off>0; off>>=1){
      const float ov = __shfl_down(v, off);
      const int   oi = __shfl_down(i, off);
      if (ov > v || (ov == v && oi < i)){ v = ov; i = oi; } // smaller p on tie
    }
    if (lane == 0){ redv[wave*GT+g] = v; redi[wave*GT+g] = i; }
  }
  __syncthreads();
  if (tid < GT){
    float v = redv[tid]; int i = redi[tid];
    for (int w=1; w<16; ++w){
      const float ov = redv[w*GT+tid]; const int oi = redi[w*GT+tid];
      if (ov > v || (ov == v && oi < i)){ v = ov; i = oi; }
    }
    best[b*GT + tid] = i;
  }
}

// Kernel 2: fused assign + LSE, COALESCED-STREAM (4 rows per wave-iter).
// R9: four prior structures all hit ~110-132 us = 1.6 TB/s effective read
// BW, while fills write 6.8 TB/s and float4 copy reads 6.3 TB/s. Shared
// defect: either coalesced-loads-via-LDS-serialization (R0-R5) or
// de-coalesced direct loads (R6/R8: 64 scattered lines/VMEM inst). This
// version finally matches the fast references: 4 rows = 324 floats =
// EXACTLY 81 aligned float4s (and P%4==0 so a group never straddles a
// batch). Lane i reads f4[81t+i], lane<17 reads f4[81t+64+i] -- two
// fully-coalesced VMEM insts (21 lines) per 4 rows. Per-lane exps ->
// segmented lo/hi (a lane's float4 spans <=2 consecutive rows; 2nd read
// is all row 3) -> 4x 64-lane butterfly sums. Assignment: 16 lanes/row x
// 1 GT/lane, gt data preloaded in REGISTERS (both batch slots), 16-lane
// shfl argmax (tie->smaller g == first-max) + last-wins override. No LDS
// in hot loop -> full occupancy; iterations independent.
// NOTE: __launch_bounds__(TPB) ONLY -- min-waves clause spills (R2).
__global__ __launch_bounds__(TPB) void fused_lse(
    const float* __restrict__ priors,     // (P,4) xywh
    const float* __restrict__ gt_boxes,   // (B,GT,4) xyxy
    const int*   __restrict__ gt_labels,  // (B,GT)
    const float* __restrict__ box_reg,    // (B,P,4)
    const int*   __restrict__ best,       // (B,GT)
    const float* __restrict__ logits,     // (B*P, 81)
    float* __restrict__ bg,               // (B*P)
    float* __restrict__ ce_pos,           // (B)
    float* __restrict__ sl1_sum,          // (B)
    int*   __restrict__ num_pos,          // (B)
    int P, int NG)                        // NG = B*P/4 groups of 4 rows
{
  __shared__ float sgx0[2][GT], sgy0[2][GT], sgx1[2][GT], sgy1[2][GT], sga[2][GT];
  __shared__ int   slab[2][GT], sbp[2][GT];
  const int tid = threadIdx.x;
  const int wave = tid >> 6, lane = tid & 63;
  const int G = gridDim.x;

  // contiguous group range for this block (<=69 groups -> <=2 batches)
  const int qn = NG / G, rn = NG % G;
  const int kb = blockIdx.x;
  const int t0  = kb < rn ? kb*(qn+1) : rn*(qn+1) + (kb-rn)*qn;
  const int cnt = kb < rn ? qn+1 : qn;
  if (cnt <= 0) return;
  const int tend = t0 + cnt;
  const int GP = P >> 2;                  // groups per batch (P%4==0)
  const int b0 = t0 / GP;
  const int b1 = (tend - 1) / GP;         // <= b0+1
  const int boundary_g = b1 * GP;         // t >= boundary_g -> slot 1

  if (tid < 2*GT){                        // stage gt data for both batches
    const int slot = tid >> 4, g = tid & 15;
    const int bb = slot ? b1 : b0;
    const float4 gb = ((const float4*)gt_boxes)[bb*GT + g];
    sgx0[slot][g]=gb.x; sgy0[slot][g]=gb.y; sgx1[slot][g]=gb.z; sgy1[slot][g]=gb.w;
    sga[slot][g] = (gb.z-gb.x)*(gb.w-gb.y);
    slab[slot][g] = gt_labels[bb*GT + g];
    sbp[slot][g]  = best[bb*GT + g];
  }
  __syncthreads();                        // one-time; hot loop has no LDS deps

  // per-lane register preload of gt box for GT index (lane&15), both slots
  const int L  = lane >> 4;               // local row 0..3 this lane assigns
  const int sq = lane & 15;               // GT index this lane covers
  const float Agx0 = sgx0[0][sq], Agy0 = sgy0[0][sq],
              Agx1 = sgx1[0][sq], Agy1 = sgy1[0][sq], Aga = sga[0][sq];
  const float Bgx0 = sgx0[1][sq], Bgy0 = sgy0[1][sq],
              Bgx1 = sgx1[1][sq], Bgy1 = sgy1[1][sq], Bga = sga[1][sq];
  const int Abp = sbp[0][sq], Bbp = sbp[1][sq];

  // segmented-sum constants for this lane
  const int lf0 = lane * 4;               // local float index of v.x (0..255)
  const int r_lo = (lf0 >= 81) + (lf0 >= 162) + (lf0 >= 243);
  const int bound = 81 * (r_lo + 1);
  const float4* lg4 = (const float4*)logits;

  for (int t = t0 + wave; t < tend; t += 4){   // one 4-row group per wave
    const int slot = (t >= boundary_g);
    const int b = slot ? b1 : b0;
    const int g0row = t * 4;              // global row of local row 0
    const int pbase = g0row - b * P;      // prior index of local row 0
    const long long fbase = 81LL * t;

    float4 v = lg4[fbase + lane];         // coalesced: 64 consecutive f4
    float4 v2;
    if (lane < 17) v2 = lg4[fbase + 64 + lane];   // coalesced tail (17 f4)

    const int p = pbase + L;
    const float4 pr = ((const float4*)priors)[p];          // 4 distinct lines
    const float4 br = ((const float4*)box_reg)[g0row + L]; // 4 distinct lines

    // ---- per-lane segmented exp sums (rows r_lo / r_lo+1) ----
    float lo = 0.0f, hi = 0.0f;
    { const float e = __expf(v.x); if (lf0+0 >= bound) hi += e; else lo += e; }
    { const float e = __expf(v.y); if (lf0+1 >= bound) hi += e; else lo += e; }
    { const float e = __expf(v.z); if (lf0+2 >= bound) hi += e; else lo += e; }
    { const float e = __expf(v.w); if (lf0+3 >= bound) hi += e; else lo += e; }
    float s2 = 0.0f;                       // 2nd read: floats 256..323, all row 3
    if (lane < 17)
      s2 = __expf(v2.x) + __expf(v2.y) + __expf(v2.z) + __expf(v2.w);

    float a0 = (r_lo == 0) ? lo : 0.0f;
    float a1 = (r_lo == 0) ? hi : ((r_lo == 1) ? lo : 0.0f);
    float a2 = (r_lo == 1) ? hi : ((r_lo == 2) ? lo : 0.0f);
    float a3 = ((r_lo == 2) ? hi : ((r_lo == 3) ? lo : 0.0f)) + s2;

    #pragma unroll
    for (int m = 1; m < 64; m <<= 1){      // 4 independent wave sums
      a0 += __shfl_xor(a0, m);
      a1 += __shfl_xor(a1, m);
      a2 += __shfl_xor(a2, m);
      a3 += __shfl_xor(a3, m);
    }

    // class-0 logit of each local row: float 81r -> f4 idx 20r, elem r
    float cand = v.x;
    if (lane == 20) cand = v.y;
    else if (lane == 40) cand = v.z;
    else if (lane == 60) cand = v.w;
    const float x00 = __shfl(cand, 0);
    const float x01 = __shfl(cand, 20);
    const float x02 = __shfl(cand, 40);
    const float x03 = __shfl(cand, 60);

    const float l0 = __logf(a0), l1 = __logf(a1),
                l2 = __logf(a2), l3 = __logf(a3);

    // ---- assignment: 16 lanes per row, 1 GT per lane ----
    const float gx0v = slot ? Bgx0 : Agx0, gy0v = slot ? Bgy0 : Agy0;
    const float gx1v = slot ? Bgx1 : Agx1, gy1v = slot ? Bgy1 : Agy1;
    const float gav  = slot ? Bga  : Aga;
    const int   bpv  = slot ? Bbp  : Abp;

    const float px0 = pr.x - pr.z*0.5f, py0 = pr.y - pr.w*0.5f;
    const float px1 = pr.x + pr.z*0.5f, py1 = pr.y + pr.w*0.5f;
    const float pa  = (px1-px0)*(py1-py0);
    const float w = fmaxf(fminf(gx1v,px1) - fmaxf(gx0v,px0), 0.0f);
    const float h = fmaxf(fminf(gy1v,py1) - fmaxf(gy0v,py0), 0.0f);
    const float inter = w*h;
    float mv = inter / (gav + pa - inter);
    int mi = sq;
    #pragma unroll
    for (int m = 1; m < 16; m <<= 1){      // argmax in 16-lane group
      const float omv = __shfl_xor(mv, m); // tie -> smaller g (first-max)
      const int   omi = __shfl_xor(mi, m);
      if (omv > mv || (omv == mv && omi < mi)){ mv = omv; mi = omi; }
    }
    int ovr = (bpv == p) ? sq : -1;        // best-prior override, last g wins
    #pragma unroll
    for (int m = 1; m < 16; m <<= 1) ovr = max(ovr, __shfl_xor(ovr, m));
    if (ovr >= 0){ mv = 2.0f; mi = ovr; }

    if (sq == 0){                          // one lane per row finishes
      const float lseL = (L==0) ? l0 : (L==1) ? l1 : (L==2) ? l2 : l3;
      const float x0L  = (L==0) ? x00 : (L==1) ? x01 : (L==2) ? x02 : x03;
      int lab = 0; float sl1v = 0.0f;
      if (mv >= 0.5f){
        lab = slab[slot][mi];
        const float gbx0 = sgx0[slot][mi], gby0 = sgy0[slot][mi];
        const float gbx1 = sgx1[slot][mi], gby1 = sgy1[slot][mi];
        const float ctrx = (gbx0+gbx1)*0.5f, ctry = (gby0+gby1)*0.5f;
        const float wx = gbx1-gbx0, wy = gby1-gby0;
        const float tx = (ctrx - pr.x) / (0.1f*pr.z);
        const float ty = (ctry - pr.y) / (0.1f*pr.w);
        const float tw = __logf(wx/pr.z) / 0.2f;
        const float th = __logf(wy/pr.w) / 0.2f;
        sl1v = smoothl1(br.x - tx) + smoothl1(br.y - ty)
             + smoothl1(br.z - tw) + smoothl1(br.w - th);
      }
      float outv;
      if (lab > 0){
        atomicAdd(&ce_pos[b], lseL - logits[(long long)(g0row+L)*NCLS + lab]);
        atomicAdd(&sl1_sum[b], sl1v);
        atomicAdd(&num_pos[b], 1);
        outv = 0.0f;
      } else {
        outv = fmaxf(lseL - x0L, 0.0f);    // clamp: radix needs >=0
      }
      bg[g0row + L] = outv;                // 4 consecutive dwords per wave
    }
  }
}

// Kernel 3: per-batch top-(3*num_pos) sum. Count-only 8-bit radix select
// (16 replicated histograms, stride 257), final pass sums values strictly
// above threshold; ties contribute krem * threshold. Fused final /N reduce.
__global__ __launch_bounds__(TPB) void topk_kernel(
    const float* __restrict__ bg,
    const int*   __restrict__ num_pos,
    const float* __restrict__ sl1_sum,
    const float* __restrict__ ce_pos,
    float* __restrict__ out,
    int P, int B)
{
  const int b = blockIdx.x;
  const int tid = threadIdx.x;
  const int wave = tid >> 6, lane = tid & 63;
  const int rep = tid & 15;
  __shared__ float sv[MAXP];
  __shared__ unsigned cntR[16][257];    // padded: bank = (rep*257+bin)%32
  __shared__ unsigned s_wc[4];
  __shared__ float    s_wf[4];
  __shared__ unsigned s_prefix;
  __shared__ int s_krem, s_chosen, s_newk;

  {
    const float4* srcp = (const float4*)(bg + (long long)b * P);
    float4* dst = (float4*)sv;
    for (int j = tid; j < P/4; j += TPB) dst[j] = srcp[j];
  }
  if (tid == 0){
    const int k = 3*num_pos[b];
    s_krem = k < P ? k : P-1;
    s_prefix = 0u;
  }
  __syncthreads();

  for (int level=0; level<4; ++level){
    const int shift = 24 - 8*level;
    for (int i = tid; i < 16*257; i += TPB) ((unsigned*)cntR)[i] = 0u;
    __syncthreads();
    const unsigned pref = s_prefix;
    const int k = s_krem;
    for (int j = tid; j < P/4; j += TPB){
      const float4 f4 = ((const float4*)sv)[j];
      #pragma unroll
      for (int e=0; e<4; ++e){
        const unsigned key = __float_as_uint((&f4.x)[e]);
        const bool ok = (level == 0) || ((key >> (shift+8)) == pref);
        if (ok) atomicAdd(&cntR[rep][(key >> shift) & 255u], 1u);
      }
    }
    __syncthreads();
    const int rb = 255 - tid;
    unsigned c = 0;
    #pragma unroll
    for (int r=0; r<16; ++r) c += cntR[r][rb];
    unsigned cv = c;
    #pragma unroll
    for (int off=1; off<64; off<<=1){
      const unsigned oc = __shfl_up(cv, off);
      if (lane >= off) cv += oc;
    }
    if (lane == 63) s_wc[wave] = cv;
    __syncthreads();
    unsigned addc = 0;
    for (int w=0; w<4; ++w) if (w < wave) addc += s_wc[w];
    const unsigned S = cv - c + addc;   // count in bins > rb (matching prefix)
    if ((int)S <= k && k < (int)(S + c)){
      s_chosen = rb; s_newk = k - (int)S;      // exactly one thread
    }
    __syncthreads();
    if (tid == 0){
      s_krem = s_newk;
      s_prefix = (pref << 8) | (unsigned)s_chosen;
    }
    __syncthreads();
  }
  // final pass: sum of values strictly above threshold
  const unsigned T = s_prefix;
  float acc = 0.0f;
  for (int j = tid; j < P/4; j += TPB){
    const float4 f4 = ((const float4*)sv)[j];
    #pragma unroll
    for (int e=0; e<4; ++e){
      const float f = (&f4.x)[e];
      if (__float_as_uint(f) > T) acc += f;
    }
  }
  for (int off=32; off>0; off>>=1) acc += __shfl_down(acc, off);
  if (lane == 0) s_wf[wave] = acc;
  __syncthreads();
  if (tid < 64){                        // wave 0: N = sum(num_pos), /N shares
    float n = 0.0f;
    for (int i = tid; i < B; i += 64) n += (float)num_pos[i];
    for (int off=32; off>0; off>>=1) n += __shfl_down(n, off);
    if (tid == 0){
      const float N = n;
      const float cls = s_wf[0]+s_wf[1]+s_wf[2]+s_wf[3]
                      + (float)s_krem * __uint_as_float(T);
      atomicAdd(&out[0], sl1_sum[b] / N);
      atomicAdd(&out[1], (ce_pos[b] + cls) / N);
    }
  }
}

extern "C" void kernel_launch(void* const* d_in, const int* in_sizes, int n_in,
                              void* d_out, int out_size, void* d_ws, size_t ws_size,
                              hipStream_t stream) {
  const float* priors = (const float*)d_in[0];
  const float* logits = (const float*)d_in[1];
  const float* boxreg = (const float*)d_in[2];
  const float* gtb    = (const float*)d_in[3];
  const int*   gtl    = (const int*)d_in[4];
  const int P = in_sizes[0] / 4;          // 8732
  const int B = in_sizes[4] / GT;         // 64
  const long long BP = (long long)B * P;

  char* ws = (char*)d_ws;
  float* bgv  = (float*)ws;                             // BP float
  int*   best = (int*)(ws + BP*4);                      // B*GT int
  float* sl1_s= (float*)(ws + BP*4 + 4096);
  int*   npos = (int*)  (ws + BP*4 + 4352);
  float* cep  = (float*)(ws + BP*4 + 4608);

  bestprior<<<B, BPT, 0, stream>>>(priors, gtb, best, cep, sl1_s, npos,
                                   (float*)d_out, P);
  const int NG = (int)(BP / 4);           // 139,712 four-row groups
  const int G = 2048;                     // 8 blocks/CU, ~17 groups/wave
  fused_lse<<<G, TPB, 0, stream>>>(priors, gtb, gtl, boxreg, best, logits,
                                   bgv, cep, sl1_s, npos, P, NG);
  topk_kernel<<<B, TPB, 0, stream>>>(bgv, npos, sl1_s, cep, (float*)d_out, P, B);
}